// Round 8
// baseline (786.286 us; speedup 1.0000x reference)
//
#include <hip/hip_runtime.h>

#define LOG2E 1.44269504088896340736f
#define TOPK 409

typedef __attribute__((ext_vector_type(8))) short bf16x8;
typedef __attribute__((ext_vector_type(4))) float f32x4;
typedef __attribute__((ext_vector_type(4))) unsigned short us4;

__device__ __forceinline__ unsigned short f2bf(float f) {
    unsigned u = __float_as_uint(f);
    unsigned r = (u + 0x7fffu + ((u >> 16) & 1u)) >> 16;   // RNE
    return (unsigned short)r;
}
__device__ __forceinline__ float bf2f(unsigned short h) {
    return __uint_as_float(((unsigned)h) << 16);
}

// Async global->LDS, 16B per lane. LDS dest must be wave-uniform base + lane*16
// (our staging layouts are linear in tid, so this holds by construction).
__device__ __forceinline__ void gl_lds16(const unsigned short* g, unsigned short* l) {
    __builtin_amdgcn_global_load_lds(
        (const __attribute__((address_space(1))) unsigned int*)(const void*)g,
        (__attribute__((address_space(3))) unsigned int*)(void*)l, 16, 0, 0);
}

// ---------------------------------------------------------------------------
// Cast X fp32 -> Xhi/Xlo bf16 (grid covers 6291456 elements exactly)
// ---------------------------------------------------------------------------
__global__ __launch_bounds__(256) void cast_x_kernel(
    const float* __restrict__ X, unsigned short* __restrict__ Xhi,
    unsigned short* __restrict__ Xlo)
{
    int i = (blockIdx.x * 256 + threadIdx.x) * 8;
    float4 a = *(const float4*)&X[i];
    float4 b = *(const float4*)&X[i + 4];
    float v[8] = {a.x, a.y, a.z, a.w, b.x, b.y, b.z, b.w};
    us4 h0, h1, l0, l1;
#pragma unroll
    for (int k = 0; k < 4; ++k) {
        unsigned short hb = f2bf(v[k]);
        h0[k] = hb; l0[k] = f2bf(v[k] - bf2f(hb));
        unsigned short hb2 = f2bf(v[4 + k]);
        h1[k] = hb2; l1[k] = f2bf(v[4 + k] - bf2f(hb2));
    }
    *(us4*)&Xhi[i] = h0; *(us4*)&Xhi[i + 4] = h1;
    *(us4*)&Xlo[i] = l0; *(us4*)&Xlo[i + 4] = l1;
}

// ---------------------------------------------------------------------------
// W[K,N] fp32 -> Th/Tl[N,K] bf16 (transpose + hi/lo split), 32x32 LDS tiles
// ---------------------------------------------------------------------------
__global__ __launch_bounds__(256) void transpose_split_kernel(
    const float* __restrict__ W, unsigned short* __restrict__ Th,
    unsigned short* __restrict__ Tl, int K, int N)
{
    __shared__ float T[32][33];
    const int tx = threadIdx.x & 31, ty = threadIdx.x >> 5;   // ty 0..7
    const int n0 = blockIdx.x * 32, k0 = blockIdx.y * 32;
#pragma unroll
    for (int r = 0; r < 4; ++r)
        T[ty + r * 8][tx] = W[(size_t)(k0 + ty + r * 8) * N + n0 + tx];
    __syncthreads();
#pragma unroll
    for (int r = 0; r < 4; ++r) {
        int nl = ty + r * 8;
        float v = T[tx][nl];
        unsigned short hb = f2bf(v);
        Th[(size_t)(n0 + nl) * K + k0 + tx] = hb;
        Tl[(size_t)(n0 + nl) * K + k0 + tx] = f2bf(v - bf2f(hb));
    }
}

// ---------------------------------------------------------------------------
// QKV GEMM via MFMA, staging via global_load_lds width=16 (kept).
// ---------------------------------------------------------------------------
__global__ __launch_bounds__(256) void qkv_mfma_kernel(
    const unsigned short* __restrict__ Xhi, const unsigned short* __restrict__ Xlo,
    const unsigned short* __restrict__ Bhg, const unsigned short* __restrict__ Blg,
    const float* __restrict__ bias,
    unsigned short* __restrict__ Qhi, unsigned short* __restrict__ Qlo,
    unsigned short* __restrict__ Khi, unsigned short* __restrict__ Klo,
    unsigned short* __restrict__ Vt)
{
    __shared__ unsigned short Ah[128 * 32], Al[128 * 32];
    __shared__ unsigned short Bh[128 * 32], Bl[128 * 32];
    const int tid = threadIdx.x;
    const int n0 = blockIdx.x * 128, m0 = blockIdx.y * 128;
    const int which = n0 / 768;               // block-uniform
    const bool threep = (which < 2);
    const int lane = tid & 63, l16 = lane & 15, quad = lane >> 4;
    const int w = tid >> 6, wm = w >> 1, wn = w & 1;

    f32x4 acc[4][4];
#pragma unroll
    for (int mi = 0; mi < 4; ++mi)
#pragma unroll
        for (int ni = 0; ni < 4; ++ni) acc[mi][ni] = (f32x4){0.f, 0.f, 0.f, 0.f};

    const int r0 = tid >> 2, kc = (tid & 3) * 8;   // staging: rows r0, r0+64
    const int r1 = r0 + 64;

    for (int k0 = 0; k0 < 768; k0 += 32) {
        __syncthreads();   // previous tile's LDS reads complete
        gl_lds16(&Xhi[(size_t)(m0 + r0) * 768 + k0 + kc], &Ah[r0 * 32 + kc]);
        gl_lds16(&Xhi[(size_t)(m0 + r1) * 768 + k0 + kc], &Ah[r1 * 32 + kc]);
        gl_lds16(&Bhg[(size_t)(n0 + r0) * 768 + k0 + kc], &Bh[r0 * 32 + kc]);
        gl_lds16(&Bhg[(size_t)(n0 + r1) * 768 + k0 + kc], &Bh[r1 * 32 + kc]);
        if (threep) {
            gl_lds16(&Xlo[(size_t)(m0 + r0) * 768 + k0 + kc], &Al[r0 * 32 + kc]);
            gl_lds16(&Xlo[(size_t)(m0 + r1) * 768 + k0 + kc], &Al[r1 * 32 + kc]);
            gl_lds16(&Blg[(size_t)(n0 + r0) * 768 + k0 + kc], &Bl[r0 * 32 + kc]);
            gl_lds16(&Blg[(size_t)(n0 + r1) * 768 + k0 + kc], &Bl[r1 * 32 + kc]);
        }
        __syncthreads();   // implicit vmcnt(0) drain -> LDS tile ready

        bf16x8 fah[4], fal[4];
#pragma unroll
        for (int mi = 0; mi < 4; ++mi) {
            int off = (wm * 64 + mi * 16 + l16) * 32 + quad * 8;
            fah[mi] = *(const bf16x8*)&Ah[off];
            if (threep) fal[mi] = *(const bf16x8*)&Al[off];
        }
#pragma unroll
        for (int ni = 0; ni < 4; ++ni) {
            int off = (wn * 64 + ni * 16 + l16) * 32 + quad * 8;
            bf16x8 fbh = *(const bf16x8*)&Bh[off];
            if (threep) {
                bf16x8 fbl = *(const bf16x8*)&Bl[off];
#pragma unroll
                for (int mi = 0; mi < 4; ++mi) {
                    acc[mi][ni] = __builtin_amdgcn_mfma_f32_16x16x32_bf16(fah[mi], fbh, acc[mi][ni], 0, 0, 0);
                    acc[mi][ni] = __builtin_amdgcn_mfma_f32_16x16x32_bf16(fah[mi], fbl, acc[mi][ni], 0, 0, 0);
                    acc[mi][ni] = __builtin_amdgcn_mfma_f32_16x16x32_bf16(fal[mi], fbh, acc[mi][ni], 0, 0, 0);
                }
            } else {
#pragma unroll
                for (int mi = 0; mi < 4; ++mi)
                    acc[mi][ni] = __builtin_amdgcn_mfma_f32_16x16x32_bf16(fah[mi], fbh, acc[mi][ni], 0, 0, 0);
            }
        }
    }

#pragma unroll
    for (int mi = 0; mi < 4; ++mi) {
#pragma unroll
        for (int ni = 0; ni < 4; ++ni) {
            int nb = n0 + wn * 64 + ni * 16 + l16;
            int rem = nb - which * 768;
            int h = rem >> 6, d = rem & 63;
            float bv = bias[nb];
#pragma unroll
            for (int r = 0; r < 4; ++r) {
                int m = m0 + wm * 64 + mi * 16 + quad * 4 + r;
                int bb = m >> 10, s = m & 1023;
                int head = bb * 12 + h;
                float val = acc[mi][ni][r] + bv;
                if (which == 2) {
                    Vt[(size_t)head * 65536 + (size_t)d * 1024 + s] = f2bf(val);
                } else {
                    unsigned short hb = f2bf(val);
                    unsigned short lb = f2bf(val - bf2f(hb));
                    size_t idx = (size_t)head * 65536 + (size_t)s * 64 + d;
                    if (which == 0) { Qhi[idx] = hb; Qlo[idx] = lb; }
                    else            { Khi[idx] = hb; Klo[idx] = lb; }
                }
            }
        }
    }
}

// ---------------------------------------------------------------------------
// Proj GEMM via MFMA — global_load_lds staging (kept).
// ---------------------------------------------------------------------------
__global__ __launch_bounds__(256) void proj_mfma_kernel(
    const unsigned short* __restrict__ Ag, const unsigned short* __restrict__ Bhg,
    const float* __restrict__ bias, float* __restrict__ OUT)
{
    __shared__ unsigned short Ah[128 * 32];
    __shared__ unsigned short Bh[128 * 32];
    const int tid = threadIdx.x;
    const int n0 = blockIdx.x * 128, m0 = blockIdx.y * 128;
    const int lane = tid & 63, l16 = lane & 15, quad = lane >> 4;
    const int w = tid >> 6, wm = w >> 1, wn = w & 1;

    f32x4 acc[4][4];
#pragma unroll
    for (int mi = 0; mi < 4; ++mi)
#pragma unroll
        for (int ni = 0; ni < 4; ++ni) acc[mi][ni] = (f32x4){0.f, 0.f, 0.f, 0.f};

    const int r0 = tid >> 2, kc = (tid & 3) * 8;
    const int r1 = r0 + 64;

    for (int k0 = 0; k0 < 768; k0 += 32) {
        __syncthreads();
        gl_lds16(&Ag[(size_t)(m0 + r0) * 768 + k0 + kc], &Ah[r0 * 32 + kc]);
        gl_lds16(&Ag[(size_t)(m0 + r1) * 768 + k0 + kc], &Ah[r1 * 32 + kc]);
        gl_lds16(&Bhg[(size_t)(n0 + r0) * 768 + k0 + kc], &Bh[r0 * 32 + kc]);
        gl_lds16(&Bhg[(size_t)(n0 + r1) * 768 + k0 + kc], &Bh[r1 * 32 + kc]);
        __syncthreads();

        bf16x8 fah[4];
#pragma unroll
        for (int mi = 0; mi < 4; ++mi)
            fah[mi] = *(const bf16x8*)&Ah[(wm * 64 + mi * 16 + l16) * 32 + quad * 8];
#pragma unroll
        for (int ni = 0; ni < 4; ++ni) {
            bf16x8 fbh = *(const bf16x8*)&Bh[(wn * 64 + ni * 16 + l16) * 32 + quad * 8];
#pragma unroll
            for (int mi = 0; mi < 4; ++mi)
                acc[mi][ni] = __builtin_amdgcn_mfma_f32_16x16x32_bf16(fah[mi], fbh, acc[mi][ni], 0, 0, 0);
        }
    }

#pragma unroll
    for (int mi = 0; mi < 4; ++mi)
#pragma unroll
        for (int ni = 0; ni < 4; ++ni) {
            int nb = n0 + wn * 64 + ni * 16 + l16;
            float bv = bias[nb];
#pragma unroll
            for (int r = 0; r < 4; ++r) {
                int m = m0 + wm * 64 + mi * 16 + quad * 4 + r;
                OUT[(size_t)m * 768 + nb] = acc[mi][ni][r] + bv;
            }
        }
}

// ---------------------------------------------------------------------------
// Attention, 512 threads (8 waves), 8 q-rows/block, ~32 KB LDS -> 4 blocks/CU.
// R7 falsified memory theories (FETCH 167->31MB, time -1.3%): the kernel is
// lockstep-stall-bound (issue util ~37%, 63% idle). This round halves the
// block: 8 q-rows, 8 waves, S = 8x1024 fp32 = 32KB -> FOUR independent
// blocks per CU (vs 2), so one block's serial phase-2 chains overlap with
// three others' MFMA/load phases. 16x16 MFMA runs with duplicated A-rows
// (l16&7): half the MFMA output is discarded — MFMA was 5.8% util, the one
// resource we can waste. Epilogue flattened (8 partials, single reduce).
// ---------------------------------------------------------------------------
__global__ __launch_bounds__(512, 8) void attn_kernel(
    const unsigned short* __restrict__ Qhi, const unsigned short* __restrict__ Qlo,
    const unsigned short* __restrict__ Khi, const unsigned short* __restrict__ Klo,
    const unsigned short* __restrict__ Vt, unsigned short* __restrict__ Aob)
{
    __shared__ float S[8 * 1024 + 16];   // 32.06 KB; aliased: Pb bf16, partials
    unsigned short* Pb = (unsigned short*)S;   // [8][1032] shorts

    // XCD swizzle: 12288 = 8*1536 (bijective). XCD c owns heads [c*12,(c+1)*12).
    const int bid = blockIdx.x;
    const int wflat = (bid & 7) * 1536 + (bid >> 3);
    const int head = wflat >> 7;     // 0..95
    const int qt = wflat & 127;      // 8-row q tile
    const int bb = head / 12, h = head - bb * 12;
    const int tid = threadIdx.x;
    const int w = tid >> 6, lane = tid & 63;   // w 0..7
    const int l16 = lane & 15, quad = lane >> 4;
    const int lr8 = l16 & 7;                   // A-operand row (dup 8-15 -> 0-7)

    const size_t hbase = (size_t)head * 65536;
    const unsigned short* Qhp = Qhi + hbase + (size_t)(qt * 8) * 64;
    const unsigned short* Qlp = Qlo + hbase + (size_t)(qt * 8) * 64;
    const unsigned short* Khp = Khi + hbase;
    const unsigned short* Klp = Klo + hbase;
    const unsigned short* Vp  = Vt + hbase;   // [64][1024]

    bf16x8 qh0, qh1, ql0, ql1;
    {
        int off = lr8 * 64 + quad * 8;
        qh0 = *(const bf16x8*)(Qhp + off);
        qh1 = *(const bf16x8*)(Qhp + off + 32);
        ql0 = *(const bf16x8*)(Qlp + off);
        ql1 = *(const bf16x8*)(Qlp + off + 32);
    }

    // ---- Phase 1: scores for cols [w*128, w*128+128) ----
    for (int t = 0; t < 8; ++t) {
        int col0 = w * 128 + t * 16;
        int off = (col0 + l16) * 64 + quad * 8;
        bf16x8 kh0 = *(const bf16x8*)(Khp + off);
        bf16x8 kh1 = *(const bf16x8*)(Khp + off + 32);
        bf16x8 kl0 = *(const bf16x8*)(Klp + off);
        bf16x8 kl1 = *(const bf16x8*)(Klp + off + 32);
        f32x4 acc = {0.f, 0.f, 0.f, 0.f};
        acc = __builtin_amdgcn_mfma_f32_16x16x32_bf16(qh0, kh0, acc, 0, 0, 0);
        acc = __builtin_amdgcn_mfma_f32_16x16x32_bf16(qh1, kh1, acc, 0, 0, 0);
        acc = __builtin_amdgcn_mfma_f32_16x16x32_bf16(qh0, kl0, acc, 0, 0, 0);
        acc = __builtin_amdgcn_mfma_f32_16x16x32_bf16(qh1, kl1, acc, 0, 0, 0);
        acc = __builtin_amdgcn_mfma_f32_16x16x32_bf16(ql0, kh0, acc, 0, 0, 0);
        acc = __builtin_amdgcn_mfma_f32_16x16x32_bf16(ql1, kh1, acc, 0, 0, 0);
        if (quad < 2) {   // rows 0..7 are the valid half of the 16x16 output
#pragma unroll
            for (int r = 0; r < 4; ++r)
                S[(quad * 4 + r) * 1024 + col0 + l16] = acc[r] * 0.125f;
        }
    }
    __syncthreads();

    // ---- Phase 2: wave w owns row w; 16 values/lane ----
    float rs;
    {
        const float* Srow = &S[w << 10];
        float f[16];
        float m = -1e30f, mn = 1e30f;
#pragma unroll
        for (int i = 0; i < 4; ++i) {
            f32x4 v = *(const f32x4*)&Srow[(lane + (i << 6)) << 2];
#pragma unroll
            for (int k = 0; k < 4; ++k) {
                float x = v[k];
                f[i * 4 + k] = x;
                m = fmaxf(m, x);
                mn = fminf(mn, x);
            }
        }
        __syncthreads();   // all S fp32 reads done; Pb writes become safe

#pragma unroll
        for (int off = 32; off; off >>= 1) {
            m = fmaxf(m, __shfl_xor(m, off));
            mn = fminf(mn, __shfl_xor(mn, off));
        }

        // Value-space bisection for the TOPK-th largest value (exact; kept).
        float lo = mn, hi = m;
#pragma unroll 1
        for (int it = 0; it < 64; ++it) {
            float mid = 0.5f * (lo + hi);
            if (mid == lo || mid == hi) break;   // bracket collapsed: exact
            int cnt = 0;
#pragma unroll
            for (int i = 0; i < 16; ++i)
                cnt += (int)__popcll(__ballot(f[i] >= mid));
            if (cnt >= TOPK) {
                lo = mid;
                if (cnt == TOPK) break;          // mid lies in the gap: exact
            } else {
                hi = mid;
            }
        }
        const float thr = lo;

        // masked exp (base = row max), write P as bf16 into Pb
        float ssum = 0.f;
#pragma unroll
        for (int i = 0; i < 4; ++i) {
            us4 eh;
#pragma unroll
            for (int k = 0; k < 4; ++k) {
                float x = f[i * 4 + k];
                float ev = (x >= thr) ? exp2f((x - m) * LOG2E) : 0.f;
                ssum += ev;
                eh[k] = f2bf(ev);
            }
            *(us4*)&Pb[w * 1032 + 4 * lane + 256 * i] = eh;
        }
#pragma unroll
        for (int off = 32; off; off >>= 1) ssum += __shfl_xor(ssum, off);
        rs = ssum;
    }
    __syncthreads();

    // ---- Phase 3: partial O over k in [w*128, w*128+128), 4 steps ----
    f32x4 oacc[4];
#pragma unroll
    for (int nt = 0; nt < 4; ++nt) oacc[nt] = (f32x4){0.f, 0.f, 0.f, 0.f};

    for (int step = 0; step < 4; ++step) {
        int k0 = w * 128 + step * 32;
        bf16x8 a = *(const bf16x8*)&Pb[lr8 * 1032 + k0 + quad * 8];
#pragma unroll
        for (int nt = 0; nt < 4; ++nt) {
            bf16x8 bfrag = *(const bf16x8*)(Vp + (size_t)(nt * 16 + l16) * 1024 + k0 + quad * 8);
            oacc[nt] = __builtin_amdgcn_mfma_f32_16x16x32_bf16(a, bfrag, oacc[nt], 0, 0, 0);
        }
    }
    __syncthreads();   // all Pb reads done; S region reusable

    // All 8 waves write their partials (valid rows 0..7 = quads 0,1); rsum.
    if (quad < 2) {
#pragma unroll
        for (int nt = 0; nt < 4; ++nt)
#pragma unroll
            for (int r = 0; r < 4; ++r)
                S[((w << 3) + quad * 4 + r) * 68 + nt * 16 + l16] = oacc[nt][r];
    }
    if (lane == 0) S[8192 + w] = rs;
    __syncthreads();

    if (tid < 128) {
        int row = tid >> 4, ds = (tid & 15) * 4;
        f32x4 o = {0.f, 0.f, 0.f, 0.f};
#pragma unroll
        for (int ww = 0; ww < 8; ++ww)
            o += *(const f32x4*)&S[((ww << 3) + row) * 68 + ds];
        float inv = 1.f / S[8192 + row];
        int srow = qt * 8 + row;
        us4 res;
#pragma unroll
        for (int k = 0; k < 4; ++k) res[k] = f2bf(o[k] * inv);
        *(us4*)&Aob[((size_t)(bb * 1024 + srow)) * 768 + h * 64 + ds] = res;
    }
}

extern "C" void kernel_launch(void* const* d_in, const int* in_sizes, int n_in,
                              void* d_out, int out_size, void* d_ws, size_t ws_size,
                              hipStream_t stream)
{
    const float* X     = (const float*)d_in[0];
    const float* Wqkv  = (const float*)d_in[1];
    const float* bqkv  = (const float*)d_in[2];
    const float* Wproj = (const float*)d_in[3];
    const float* bproj = (const float*)d_in[4];
    float* out = (float*)d_out;

    unsigned short* us = (unsigned short*)d_ws;
    const size_t P = (size_t)8192 * 768;          // 6291456
    unsigned short* Xhi = us;
    unsigned short* Xlo = Xhi + P;
    unsigned short* Wqh = Xlo + P;                // [2304][768]
    unsigned short* Wql = Wqh + (size_t)2304 * 768;
    unsigned short* Wph = Wql + (size_t)2304 * 768;  // [768][768]
    unsigned short* Wpl = Wph + (size_t)768 * 768;
    unsigned short* Qhi = Wpl + (size_t)768 * 768;
    unsigned short* Qlo = Qhi + P;
    unsigned short* Khi = Qlo + P;
    unsigned short* Klo = Khi + P;
    unsigned short* Vt  = Klo + P;
    unsigned short* Aob = Xhi;   // reuse: X consumed by qkv before attn writes Aob

    cast_x_kernel<<<3072, 256, 0, stream>>>(X, Xhi, Xlo);
    transpose_split_kernel<<<dim3(72, 24), 256, 0, stream>>>(Wqkv, Wqh, Wql, 768, 2304);
    transpose_split_kernel<<<dim3(24, 24), 256, 0, stream>>>(Wproj, Wph, Wpl, 768, 768);
    qkv_mfma_kernel<<<dim3(18, 64), 256, 0, stream>>>(Xhi, Xlo, Wqh, Wql, bqkv,
                                                      Qhi, Qlo, Khi, Klo, Vt);
    attn_kernel<<<12288, 512, 0, stream>>>(Qhi, Qlo, Khi, Klo, Vt, Aob);
    proj_mfma_kernel<<<dim3(6, 64), 256, 0, stream>>>(Aob, Wph, bproj, out);
}

// Round 9
// 419.527 us; speedup vs baseline: 1.8742x; 1.8742x over previous
//
#include <hip/hip_runtime.h>

#define LOG2E 1.44269504088896340736f
#define TOPK 409

typedef __attribute__((ext_vector_type(8))) short bf16x8;
typedef __attribute__((ext_vector_type(4))) float f32x4;
typedef __attribute__((ext_vector_type(4))) unsigned short us4;

__device__ __forceinline__ unsigned short f2bf(float f) {
    unsigned u = __float_as_uint(f);
    unsigned r = (u + 0x7fffu + ((u >> 16) & 1u)) >> 16;   // RNE
    return (unsigned short)r;
}
__device__ __forceinline__ float bf2f(unsigned short h) {
    return __uint_as_float(((unsigned)h) << 16);
}

// Async global->LDS, 16B per lane. LDS dest must be wave-uniform base + lane*16.
__device__ __forceinline__ void gl_lds16(const unsigned short* g, unsigned short* l) {
    __builtin_amdgcn_global_load_lds(
        (const __attribute__((address_space(1))) unsigned int*)(const void*)g,
        (__attribute__((address_space(3))) unsigned int*)(void*)l, 16, 0, 0);
}

// ---------------------------------------------------------------------------
// Cast X fp32 -> Xhi/Xlo bf16 (grid covers 6291456 elements exactly)
// ---------------------------------------------------------------------------
__global__ __launch_bounds__(256) void cast_x_kernel(
    const float* __restrict__ X, unsigned short* __restrict__ Xhi,
    unsigned short* __restrict__ Xlo)
{
    int i = (blockIdx.x * 256 + threadIdx.x) * 8;
    float4 a = *(const float4*)&X[i];
    float4 b = *(const float4*)&X[i + 4];
    float v[8] = {a.x, a.y, a.z, a.w, b.x, b.y, b.z, b.w};
    us4 h0, h1, l0, l1;
#pragma unroll
    for (int k = 0; k < 4; ++k) {
        unsigned short hb = f2bf(v[k]);
        h0[k] = hb; l0[k] = f2bf(v[k] - bf2f(hb));
        unsigned short hb2 = f2bf(v[4 + k]);
        h1[k] = hb2; l1[k] = f2bf(v[4 + k] - bf2f(hb2));
    }
    *(us4*)&Xhi[i] = h0; *(us4*)&Xhi[i + 4] = h1;
    *(us4*)&Xlo[i] = l0; *(us4*)&Xlo[i + 4] = l1;
}

// ---------------------------------------------------------------------------
// W[K,N] fp32 -> Th/Tl[N,K] bf16 (transpose + hi/lo split), 32x32 LDS tiles
// ---------------------------------------------------------------------------
__global__ __launch_bounds__(256) void transpose_split_kernel(
    const float* __restrict__ W, unsigned short* __restrict__ Th,
    unsigned short* __restrict__ Tl, int K, int N)
{
    __shared__ float T[32][33];
    const int tx = threadIdx.x & 31, ty = threadIdx.x >> 5;   // ty 0..7
    const int n0 = blockIdx.x * 32, k0 = blockIdx.y * 32;
#pragma unroll
    for (int r = 0; r < 4; ++r)
        T[ty + r * 8][tx] = W[(size_t)(k0 + ty + r * 8) * N + n0 + tx];
    __syncthreads();
#pragma unroll
    for (int r = 0; r < 4; ++r) {
        int nl = ty + r * 8;
        float v = T[tx][nl];
        unsigned short hb = f2bf(v);
        Th[(size_t)(n0 + nl) * K + k0 + tx] = hb;
        Tl[(size_t)(n0 + nl) * K + k0 + tx] = f2bf(v - bf2f(hb));
    }
}

// ---------------------------------------------------------------------------
// QKV GEMM via MFMA, global_load_lds staging (kept).
// This round: K and V are written in MFMA-FRAGMENT-MAJOR layout so attn's
// phase-1/3 loads are fully coalesced (1KB contiguous per wave instead of
// 16 scattered 64B touches — R8 decomposition showed phase1/3 is ~221us and
// transaction-rate-bound, not cache-bound).
//  K: idx = head*65536 + (s>>4)*1024 + (d>>3)*128 + (s&15)*8 + (d&7)
//  V: idx = head*65536 + (s>>5)*2048 + (d>>4)*512 + ((s>>3)&3)*128 + (d&15)*8 + (s&7)
// ---------------------------------------------------------------------------
__global__ __launch_bounds__(256) void qkv_mfma_kernel(
    const unsigned short* __restrict__ Xhi, const unsigned short* __restrict__ Xlo,
    const unsigned short* __restrict__ Bhg, const unsigned short* __restrict__ Blg,
    const float* __restrict__ bias,
    unsigned short* __restrict__ Qhi, unsigned short* __restrict__ Qlo,
    unsigned short* __restrict__ Khi, unsigned short* __restrict__ Klo,
    unsigned short* __restrict__ Vt)
{
    __shared__ unsigned short Ah[128 * 32], Al[128 * 32];
    __shared__ unsigned short Bh[128 * 32], Bl[128 * 32];
    const int tid = threadIdx.x;
    const int n0 = blockIdx.x * 128, m0 = blockIdx.y * 128;
    const int which = n0 / 768;               // block-uniform
    const bool threep = (which < 2);
    const int lane = tid & 63, l16 = lane & 15, quad = lane >> 4;
    const int w = tid >> 6, wm = w >> 1, wn = w & 1;

    f32x4 acc[4][4];
#pragma unroll
    for (int mi = 0; mi < 4; ++mi)
#pragma unroll
        for (int ni = 0; ni < 4; ++ni) acc[mi][ni] = (f32x4){0.f, 0.f, 0.f, 0.f};

    const int r0 = tid >> 2, kc = (tid & 3) * 8;   // staging: rows r0, r0+64
    const int r1 = r0 + 64;

    for (int k0 = 0; k0 < 768; k0 += 32) {
        __syncthreads();   // previous tile's LDS reads complete
        gl_lds16(&Xhi[(size_t)(m0 + r0) * 768 + k0 + kc], &Ah[r0 * 32 + kc]);
        gl_lds16(&Xhi[(size_t)(m0 + r1) * 768 + k0 + kc], &Ah[r1 * 32 + kc]);
        gl_lds16(&Bhg[(size_t)(n0 + r0) * 768 + k0 + kc], &Bh[r0 * 32 + kc]);
        gl_lds16(&Bhg[(size_t)(n0 + r1) * 768 + k0 + kc], &Bh[r1 * 32 + kc]);
        if (threep) {
            gl_lds16(&Xlo[(size_t)(m0 + r0) * 768 + k0 + kc], &Al[r0 * 32 + kc]);
            gl_lds16(&Xlo[(size_t)(m0 + r1) * 768 + k0 + kc], &Al[r1 * 32 + kc]);
            gl_lds16(&Blg[(size_t)(n0 + r0) * 768 + k0 + kc], &Bl[r0 * 32 + kc]);
            gl_lds16(&Blg[(size_t)(n0 + r1) * 768 + k0 + kc], &Bl[r1 * 32 + kc]);
        }
        __syncthreads();   // implicit vmcnt(0) drain -> LDS tile ready

        bf16x8 fah[4], fal[4];
#pragma unroll
        for (int mi = 0; mi < 4; ++mi) {
            int off = (wm * 64 + mi * 16 + l16) * 32 + quad * 8;
            fah[mi] = *(const bf16x8*)&Ah[off];
            if (threep) fal[mi] = *(const bf16x8*)&Al[off];
        }
#pragma unroll
        for (int ni = 0; ni < 4; ++ni) {
            int off = (wn * 64 + ni * 16 + l16) * 32 + quad * 8;
            bf16x8 fbh = *(const bf16x8*)&Bh[off];
            if (threep) {
                bf16x8 fbl = *(const bf16x8*)&Bl[off];
#pragma unroll
                for (int mi = 0; mi < 4; ++mi) {
                    acc[mi][ni] = __builtin_amdgcn_mfma_f32_16x16x32_bf16(fah[mi], fbh, acc[mi][ni], 0, 0, 0);
                    acc[mi][ni] = __builtin_amdgcn_mfma_f32_16x16x32_bf16(fah[mi], fbl, acc[mi][ni], 0, 0, 0);
                    acc[mi][ni] = __builtin_amdgcn_mfma_f32_16x16x32_bf16(fal[mi], fbh, acc[mi][ni], 0, 0, 0);
                }
            } else {
#pragma unroll
                for (int mi = 0; mi < 4; ++mi)
                    acc[mi][ni] = __builtin_amdgcn_mfma_f32_16x16x32_bf16(fah[mi], fbh, acc[mi][ni], 0, 0, 0);
            }
        }
    }

#pragma unroll
    for (int mi = 0; mi < 4; ++mi) {
#pragma unroll
        for (int ni = 0; ni < 4; ++ni) {
            int nb = n0 + wn * 64 + ni * 16 + l16;
            int rem = nb - which * 768;
            int h = rem >> 6, d = rem & 63;
            float bv = bias[nb];
#pragma unroll
            for (int r = 0; r < 4; ++r) {
                int m = m0 + wm * 64 + mi * 16 + quad * 4 + r;
                int bb = m >> 10, s = m & 1023;
                int head = bb * 12 + h;
                float val = acc[mi][ni][r] + bv;
                if (which == 2) {
                    size_t idx = (size_t)head * 65536 + (size_t)(s >> 5) * 2048
                               + (d >> 4) * 512 + ((s >> 3) & 3) * 128
                               + (d & 15) * 8 + (s & 7);
                    Vt[idx] = f2bf(val);
                } else {
                    unsigned short hb = f2bf(val);
                    unsigned short lb = f2bf(val - bf2f(hb));
                    if (which == 0) {
                        size_t idx = (size_t)head * 65536 + (size_t)s * 64 + d;
                        Qhi[idx] = hb; Qlo[idx] = lb;
                    } else {
                        size_t idx = (size_t)head * 65536 + (size_t)(s >> 4) * 1024
                                   + (d >> 3) * 128 + (s & 15) * 8 + (d & 7);
                        Khi[idx] = hb; Klo[idx] = lb;
                    }
                }
            }
        }
    }
}

// ---------------------------------------------------------------------------
// Proj GEMM via MFMA — global_load_lds staging (kept).
// ---------------------------------------------------------------------------
__global__ __launch_bounds__(256) void proj_mfma_kernel(
    const unsigned short* __restrict__ Ag, const unsigned short* __restrict__ Bhg,
    const float* __restrict__ bias, float* __restrict__ OUT)
{
    __shared__ unsigned short Ah[128 * 32];
    __shared__ unsigned short Bh[128 * 32];
    const int tid = threadIdx.x;
    const int n0 = blockIdx.x * 128, m0 = blockIdx.y * 128;
    const int lane = tid & 63, l16 = lane & 15, quad = lane >> 4;
    const int w = tid >> 6, wm = w >> 1, wn = w & 1;

    f32x4 acc[4][4];
#pragma unroll
    for (int mi = 0; mi < 4; ++mi)
#pragma unroll
        for (int ni = 0; ni < 4; ++ni) acc[mi][ni] = (f32x4){0.f, 0.f, 0.f, 0.f};

    const int r0 = tid >> 2, kc = (tid & 3) * 8;
    const int r1 = r0 + 64;

    for (int k0 = 0; k0 < 768; k0 += 32) {
        __syncthreads();
        gl_lds16(&Ag[(size_t)(m0 + r0) * 768 + k0 + kc], &Ah[r0 * 32 + kc]);
        gl_lds16(&Ag[(size_t)(m0 + r1) * 768 + k0 + kc], &Ah[r1 * 32 + kc]);
        gl_lds16(&Bhg[(size_t)(n0 + r0) * 768 + k0 + kc], &Bh[r0 * 32 + kc]);
        gl_lds16(&Bhg[(size_t)(n0 + r1) * 768 + k0 + kc], &Bh[r1 * 32 + kc]);
        __syncthreads();

        bf16x8 fah[4];
#pragma unroll
        for (int mi = 0; mi < 4; ++mi)
            fah[mi] = *(const bf16x8*)&Ah[(wm * 64 + mi * 16 + l16) * 32 + quad * 8];
#pragma unroll
        for (int ni = 0; ni < 4; ++ni) {
            bf16x8 fbh = *(const bf16x8*)&Bh[(wn * 64 + ni * 16 + l16) * 32 + quad * 8];
#pragma unroll
            for (int mi = 0; mi < 4; ++mi)
                acc[mi][ni] = __builtin_amdgcn_mfma_f32_16x16x32_bf16(fah[mi], fbh, acc[mi][ni], 0, 0, 0);
        }
    }

#pragma unroll
    for (int mi = 0; mi < 4; ++mi)
#pragma unroll
        for (int ni = 0; ni < 4; ++ni) {
            int nb = n0 + wn * 64 + ni * 16 + l16;
            float bv = bias[nb];
#pragma unroll
            for (int r = 0; r < 4; ++r) {
                int m = m0 + wm * 64 + mi * 16 + quad * 4 + r;
                OUT[(size_t)m * 768 + nb] = acc[mi][ni][r] + bv;
            }
        }
}

// ---------------------------------------------------------------------------
// Attention, 1024 threads (16 waves, R7 structure — proven 367us), 64 KB LDS.
// This round: K/V fragment loads read the new fragment-major layout -> each
// 1KB wave load is CONTIGUOUS (8 lines fully used) instead of touching 16
// lines at 64B each. 2x fewer VMEM transactions on the dominant (~221us)
// phase-1/3 segment. Fragment VALUES per lane are identical to R7, so the
// MFMA math is unchanged. XCD swizzle kept (6144 = 8*768, bijective).
// ---------------------------------------------------------------------------
__global__ __launch_bounds__(1024, 8) void attn_kernel(
    const unsigned short* __restrict__ Qhi, const unsigned short* __restrict__ Qlo,
    const unsigned short* __restrict__ Khi, const unsigned short* __restrict__ Klo,
    const unsigned short* __restrict__ Vt, unsigned short* __restrict__ Aob)
{
    __shared__ float S[16 * 1024];   // 64 KB. Aliased: Pb bf16 (33 KB), partials
    unsigned short* Pb = (unsigned short*)S;   // [16][1032] shorts

    const int bid = blockIdx.x;
    const int wflat = (bid & 7) * 768 + (bid >> 3);
    const int head = wflat >> 6;     // 0..95
    const int qt = wflat & 63;       // 16-row q tile
    const int bb = head / 12, h = head - bb * 12;
    const int tid = threadIdx.x;
    const int w = tid >> 6, lane = tid & 63;
    const int l16 = lane & 15, quad = lane >> 4;

    const size_t hbase = (size_t)head * 65536;
    const unsigned short* Qhp = Qhi + hbase + (size_t)(qt * 16) * 64;
    const unsigned short* Qlp = Qlo + hbase + (size_t)(qt * 16) * 64;
    const unsigned short* Khp = Khi + hbase;
    const unsigned short* Klp = Klo + hbase;
    const unsigned short* Vp  = Vt + hbase;

    bf16x8 qh0, qh1, ql0, ql1;
    {
        int off = l16 * 64 + quad * 8;
        qh0 = *(const bf16x8*)(Qhp + off);
        qh1 = *(const bf16x8*)(Qhp + off + 32);
        ql0 = *(const bf16x8*)(Qlp + off);
        ql1 = *(const bf16x8*)(Qlp + off + 32);
    }

    // Per-lane fragment offset within a 1024-elem K tile (loop-invariant).
    const int kfo = quad * 128 + l16 * 8;

    // ---- Phase 1: scores for cols [w*64, w*64+64) ----
    for (int t = 0; t < 4; ++t) {
        int T = w * 4 + t;               // 16-col tile index
        int off = T * 1024 + kfo;
        bf16x8 kh0 = *(const bf16x8*)(Khp + off);
        bf16x8 kh1 = *(const bf16x8*)(Khp + off + 512);
        bf16x8 kl0 = *(const bf16x8*)(Klp + off);
        bf16x8 kl1 = *(const bf16x8*)(Klp + off + 512);
        f32x4 acc = {0.f, 0.f, 0.f, 0.f};
        acc = __builtin_amdgcn_mfma_f32_16x16x32_bf16(qh0, kh0, acc, 0, 0, 0);
        acc = __builtin_amdgcn_mfma_f32_16x16x32_bf16(qh1, kh1, acc, 0, 0, 0);
        acc = __builtin_amdgcn_mfma_f32_16x16x32_bf16(qh0, kl0, acc, 0, 0, 0);
        acc = __builtin_amdgcn_mfma_f32_16x16x32_bf16(qh1, kl1, acc, 0, 0, 0);
        acc = __builtin_amdgcn_mfma_f32_16x16x32_bf16(ql0, kh0, acc, 0, 0, 0);
        acc = __builtin_amdgcn_mfma_f32_16x16x32_bf16(ql1, kh1, acc, 0, 0, 0);
        int col0 = w * 64 + t * 16;
#pragma unroll
        for (int r = 0; r < 4; ++r)
            S[(quad * 4 + r) * 1024 + col0 + l16] = acc[r] * 0.125f;
    }
    __syncthreads();

    // ---- Phase 2: wave w owns row w; 16 values/lane ----
    float rs;
    {
        const float* Srow = &S[w << 10];
        float f[16];
        float m = -1e30f, mn = 1e30f;
#pragma unroll
        for (int i = 0; i < 4; ++i) {
            f32x4 v = *(const f32x4*)&Srow[(lane + (i << 6)) << 2];
#pragma unroll
            for (int k = 0; k < 4; ++k) {
                float x = v[k];
                f[i * 4 + k] = x;
                m = fmaxf(m, x);
                mn = fminf(mn, x);
            }
        }
        __syncthreads();   // all S fp32 reads done; Pb writes become safe

#pragma unroll
        for (int off = 32; off; off >>= 1) {
            m = fmaxf(m, __shfl_xor(m, off));
            mn = fminf(mn, __shfl_xor(mn, off));
        }

        // Value-space bisection for the TOPK-th largest value (exact).
        float lo = mn, hi = m;
#pragma unroll 1
        for (int it = 0; it < 64; ++it) {
            float mid = 0.5f * (lo + hi);
            if (mid == lo || mid == hi) break;   // bracket collapsed: exact
            int cnt = 0;
#pragma unroll
            for (int i = 0; i < 16; ++i)
                cnt += (int)__popcll(__ballot(f[i] >= mid));
            if (cnt >= TOPK) {
                lo = mid;
                if (cnt == TOPK) break;          // mid lies in the gap: exact
            } else {
                hi = mid;
            }
        }
        const float thr = lo;

        // masked exp (base = row max), write P as bf16 into Pb
        float ssum = 0.f;
#pragma unroll
        for (int i = 0; i < 4; ++i) {
            us4 eh;
#pragma unroll
            for (int k = 0; k < 4; ++k) {
                float x = f[i * 4 + k];
                float ev = (x >= thr) ? exp2f((x - m) * LOG2E) : 0.f;
                ssum += ev;
                eh[k] = f2bf(ev);
            }
            *(us4*)&Pb[w * 1032 + 4 * lane + 256 * i] = eh;
        }
#pragma unroll
        for (int off = 32; off; off >>= 1) ssum += __shfl_xor(ssum, off);
        rs = ssum;
    }
    __syncthreads();

    // ---- Phase 3: partial O over k in [w*64, w*64+64) ----
    f32x4 oacc[4];
#pragma unroll
    for (int nt = 0; nt < 4; ++nt) oacc[nt] = (f32x4){0.f, 0.f, 0.f, 0.f};

    for (int step = 0; step < 2; ++step) {
        int k0 = w * 64 + step * 32;
        int K32 = w * 2 + step;          // 32-elem s-tile index
        bf16x8 a = *(const bf16x8*)&Pb[l16 * 1032 + k0 + quad * 8];
#pragma unroll
        for (int nt = 0; nt < 4; ++nt) {
            bf16x8 bfrag = *(const bf16x8*)(Vp + K32 * 2048 + nt * 512 + kfo);
            oacc[nt] = __builtin_amdgcn_mfma_f32_16x16x32_bf16(a, bfrag, oacc[nt], 0, 0, 0);
        }
    }
    __syncthreads();   // all Pb reads done; S region reusable

    // Stage A: waves 8..15 spill partials (rows 0..127, stride 68); rsum
    if (w >= 8) {
#pragma unroll
        for (int nt = 0; nt < 4; ++nt)
#pragma unroll
            for (int r = 0; r < 4; ++r)
                S[((w - 8) * 16 + quad * 4 + r) * 68 + nt * 16 + l16] = oacc[nt][r];
    }
    if (lane == 0) S[8704 + w] = rs;
    __syncthreads();

    // Stage B: waves 0..7 add the matching partial and write combined back
    if (w < 8) {
#pragma unroll
        for (int nt = 0; nt < 4; ++nt)
#pragma unroll
            for (int r = 0; r < 4; ++r) {
                int idx = (w * 16 + quad * 4 + r) * 68 + nt * 16 + l16;
                S[idx] = oacc[nt][r] + S[idx];
            }
    }
    __syncthreads();

    if (tid < 256) {
        int row = tid >> 4, ds = (tid & 15) * 4;
        f32x4 o = {0.f, 0.f, 0.f, 0.f};
#pragma unroll
        for (int ww = 0; ww < 8; ++ww)
            o += *(const f32x4*)&S[(ww * 16 + row) * 68 + ds];
        float inv = 1.f / S[8704 + row];
        int srow = qt * 16 + row;
        us4 res;
#pragma unroll
        for (int k = 0; k < 4; ++k) res[k] = f2bf(o[k] * inv);
        *(us4*)&Aob[((size_t)(bb * 1024 + srow)) * 768 + h * 64 + ds] = res;
    }
}

extern "C" void kernel_launch(void* const* d_in, const int* in_sizes, int n_in,
                              void* d_out, int out_size, void* d_ws, size_t ws_size,
                              hipStream_t stream)
{
    const float* X     = (const float*)d_in[0];
    const float* Wqkv  = (const float*)d_in[1];
    const float* bqkv  = (const float*)d_in[2];
    const float* Wproj = (const float*)d_in[3];
    const float* bproj = (const float*)d_in[4];
    float* out = (float*)d_out;

    unsigned short* us = (unsigned short*)d_ws;
    const size_t P = (size_t)8192 * 768;          // 6291456
    unsigned short* Xhi = us;
    unsigned short* Xlo = Xhi + P;
    unsigned short* Wqh = Xlo + P;                // [2304][768]
    unsigned short* Wql = Wqh + (size_t)2304 * 768;
    unsigned short* Wph = Wql + (size_t)2304 * 768;  // [768][768]
    unsigned short* Wpl = Wph + (size_t)768 * 768;
    unsigned short* Qhi = Wpl + (size_t)768 * 768;
    unsigned short* Qlo = Qhi + P;
    unsigned short* Khi = Qlo + P;
    unsigned short* Klo = Khi + P;
    unsigned short* Vt  = Klo + P;
    unsigned short* Aob = Xhi;   // reuse: X consumed by qkv before attn writes Aob

    cast_x_kernel<<<3072, 256, 0, stream>>>(X, Xhi, Xlo);
    transpose_split_kernel<<<dim3(72, 24), 256, 0, stream>>>(Wqkv, Wqh, Wql, 768, 2304);
    transpose_split_kernel<<<dim3(24, 24), 256, 0, stream>>>(Wproj, Wph, Wpl, 768, 768);
    qkv_mfma_kernel<<<dim3(18, 64), 256, 0, stream>>>(Xhi, Xlo, Wqh, Wql, bqkv,
                                                      Qhi, Qlo, Khi, Klo, Vt);
    attn_kernel<<<6144, 1024, 0, stream>>>(Qhi, Qlo, Khi, Klo, Vt, Aob);
    proj_mfma_kernel<<<dim3(6, 64), 256, 0, stream>>>(Aob, Wph, bproj, out);
}

// Round 10
// 417.152 us; speedup vs baseline: 1.8849x; 1.0057x over previous
//
#include <hip/hip_runtime.h>

#define LOG2E 1.44269504088896340736f
#define TOPK 409

typedef __attribute__((ext_vector_type(8))) short bf16x8;
typedef __attribute__((ext_vector_type(4))) float f32x4;
typedef __attribute__((ext_vector_type(4))) unsigned short us4;

__device__ __forceinline__ unsigned short f2bf(float f) {
    unsigned u = __float_as_uint(f);
    unsigned r = (u + 0x7fffu + ((u >> 16) & 1u)) >> 16;   // RNE
    return (unsigned short)r;
}
__device__ __forceinline__ float bf2f(unsigned short h) {
    return __uint_as_float(((unsigned)h) << 16);
}

// Async global->LDS, 16B per lane. LDS dest must be wave-uniform base + lane*16.
__device__ __forceinline__ void gl_lds16(const unsigned short* g, unsigned short* l) {
    __builtin_amdgcn_global_load_lds(
        (const __attribute__((address_space(1))) unsigned int*)(const void*)g,
        (__attribute__((address_space(3))) unsigned int*)(void*)l, 16, 0, 0);
}

// ---------------------------------------------------------------------------
// Cast X fp32 -> Xhi/Xlo bf16 (grid covers 6291456 elements exactly)
// ---------------------------------------------------------------------------
__global__ __launch_bounds__(256) void cast_x_kernel(
    const float* __restrict__ X, unsigned short* __restrict__ Xhi,
    unsigned short* __restrict__ Xlo)
{
    int i = (blockIdx.x * 256 + threadIdx.x) * 8;
    float4 a = *(const float4*)&X[i];
    float4 b = *(const float4*)&X[i + 4];
    float v[8] = {a.x, a.y, a.z, a.w, b.x, b.y, b.z, b.w};
    us4 h0, h1, l0, l1;
#pragma unroll
    for (int k = 0; k < 4; ++k) {
        unsigned short hb = f2bf(v[k]);
        h0[k] = hb; l0[k] = f2bf(v[k] - bf2f(hb));
        unsigned short hb2 = f2bf(v[4 + k]);
        h1[k] = hb2; l1[k] = f2bf(v[4 + k] - bf2f(hb2));
    }
    *(us4*)&Xhi[i] = h0; *(us4*)&Xhi[i + 4] = h1;
    *(us4*)&Xlo[i] = l0; *(us4*)&Xlo[i + 4] = l1;
}

// ---------------------------------------------------------------------------
// W[K,N] fp32 -> Th/Tl[N,K] bf16 (transpose + hi/lo split), 32x32 LDS tiles
// ---------------------------------------------------------------------------
__global__ __launch_bounds__(256) void transpose_split_kernel(
    const float* __restrict__ W, unsigned short* __restrict__ Th,
    unsigned short* __restrict__ Tl, int K, int N)
{
    __shared__ float T[32][33];
    const int tx = threadIdx.x & 31, ty = threadIdx.x >> 5;   // ty 0..7
    const int n0 = blockIdx.x * 32, k0 = blockIdx.y * 32;
#pragma unroll
    for (int r = 0; r < 4; ++r)
        T[ty + r * 8][tx] = W[(size_t)(k0 + ty + r * 8) * N + n0 + tx];
    __syncthreads();
#pragma unroll
    for (int r = 0; r < 4; ++r) {
        int nl = ty + r * 8;
        float v = T[tx][nl];
        unsigned short hb = f2bf(v);
        Th[(size_t)(n0 + nl) * K + k0 + tx] = hb;
        Tl[(size_t)(n0 + nl) * K + k0 + tx] = f2bf(v - bf2f(hb));
    }
}

// ---------------------------------------------------------------------------
// QKV GEMM via MFMA, global_load_lds staging; K/V written fragment-major
// (proven R9: attn phase-1/3 221us -> ~67us).
//  K: idx = head*65536 + (s>>4)*1024 + (d>>3)*128 + (s&15)*8 + (d&7)
//  V: idx = head*65536 + (s>>5)*2048 + (d>>4)*512 + ((s>>3)&3)*128 + (d&15)*8 + (s&7)
// ---------------------------------------------------------------------------
__global__ __launch_bounds__(256) void qkv_mfma_kernel(
    const unsigned short* __restrict__ Xhi, const unsigned short* __restrict__ Xlo,
    const unsigned short* __restrict__ Bhg, const unsigned short* __restrict__ Blg,
    const float* __restrict__ bias,
    unsigned short* __restrict__ Qhi, unsigned short* __restrict__ Qlo,
    unsigned short* __restrict__ Khi, unsigned short* __restrict__ Klo,
    unsigned short* __restrict__ Vt)
{
    __shared__ unsigned short Ah[128 * 32], Al[128 * 32];
    __shared__ unsigned short Bh[128 * 32], Bl[128 * 32];
    const int tid = threadIdx.x;
    const int n0 = blockIdx.x * 128, m0 = blockIdx.y * 128;
    const int which = n0 / 768;               // block-uniform
    const bool threep = (which < 2);
    const int lane = tid & 63, l16 = lane & 15, quad = lane >> 4;
    const int w = tid >> 6, wm = w >> 1, wn = w & 1;

    f32x4 acc[4][4];
#pragma unroll
    for (int mi = 0; mi < 4; ++mi)
#pragma unroll
        for (int ni = 0; ni < 4; ++ni) acc[mi][ni] = (f32x4){0.f, 0.f, 0.f, 0.f};

    const int r0 = tid >> 2, kc = (tid & 3) * 8;   // staging: rows r0, r0+64
    const int r1 = r0 + 64;

    for (int k0 = 0; k0 < 768; k0 += 32) {
        __syncthreads();   // previous tile's LDS reads complete
        gl_lds16(&Xhi[(size_t)(m0 + r0) * 768 + k0 + kc], &Ah[r0 * 32 + kc]);
        gl_lds16(&Xhi[(size_t)(m0 + r1) * 768 + k0 + kc], &Ah[r1 * 32 + kc]);
        gl_lds16(&Bhg[(size_t)(n0 + r0) * 768 + k0 + kc], &Bh[r0 * 32 + kc]);
        gl_lds16(&Bhg[(size_t)(n0 + r1) * 768 + k0 + kc], &Bh[r1 * 32 + kc]);
        if (threep) {
            gl_lds16(&Xlo[(size_t)(m0 + r0) * 768 + k0 + kc], &Al[r0 * 32 + kc]);
            gl_lds16(&Xlo[(size_t)(m0 + r1) * 768 + k0 + kc], &Al[r1 * 32 + kc]);
            gl_lds16(&Blg[(size_t)(n0 + r0) * 768 + k0 + kc], &Bl[r0 * 32 + kc]);
            gl_lds16(&Blg[(size_t)(n0 + r1) * 768 + k0 + kc], &Bl[r1 * 32 + kc]);
        }
        __syncthreads();   // implicit vmcnt(0) drain -> LDS tile ready

        bf16x8 fah[4], fal[4];
#pragma unroll
        for (int mi = 0; mi < 4; ++mi) {
            int off = (wm * 64 + mi * 16 + l16) * 32 + quad * 8;
            fah[mi] = *(const bf16x8*)&Ah[off];
            if (threep) fal[mi] = *(const bf16x8*)&Al[off];
        }
#pragma unroll
        for (int ni = 0; ni < 4; ++ni) {
            int off = (wn * 64 + ni * 16 + l16) * 32 + quad * 8;
            bf16x8 fbh = *(const bf16x8*)&Bh[off];
            if (threep) {
                bf16x8 fbl = *(const bf16x8*)&Bl[off];
#pragma unroll
                for (int mi = 0; mi < 4; ++mi) {
                    acc[mi][ni] = __builtin_amdgcn_mfma_f32_16x16x32_bf16(fah[mi], fbh, acc[mi][ni], 0, 0, 0);
                    acc[mi][ni] = __builtin_amdgcn_mfma_f32_16x16x32_bf16(fah[mi], fbl, acc[mi][ni], 0, 0, 0);
                    acc[mi][ni] = __builtin_amdgcn_mfma_f32_16x16x32_bf16(fal[mi], fbh, acc[mi][ni], 0, 0, 0);
                }
            } else {
#pragma unroll
                for (int mi = 0; mi < 4; ++mi)
                    acc[mi][ni] = __builtin_amdgcn_mfma_f32_16x16x32_bf16(fah[mi], fbh, acc[mi][ni], 0, 0, 0);
            }
        }
    }

#pragma unroll
    for (int mi = 0; mi < 4; ++mi) {
#pragma unroll
        for (int ni = 0; ni < 4; ++ni) {
            int nb = n0 + wn * 64 + ni * 16 + l16;
            int rem = nb - which * 768;
            int h = rem >> 6, d = rem & 63;
            float bv = bias[nb];
#pragma unroll
            for (int r = 0; r < 4; ++r) {
                int m = m0 + wm * 64 + mi * 16 + quad * 4 + r;
                int bb = m >> 10, s = m & 1023;
                int head = bb * 12 + h;
                float val = acc[mi][ni][r] + bv;
                if (which == 2) {
                    size_t idx = (size_t)head * 65536 + (size_t)(s >> 5) * 2048
                               + (d >> 4) * 512 + ((s >> 3) & 3) * 128
                               + (d & 15) * 8 + (s & 7);
                    Vt[idx] = f2bf(val);
                } else {
                    unsigned short hb = f2bf(val);
                    unsigned short lb = f2bf(val - bf2f(hb));
                    if (which == 0) {
                        size_t idx = (size_t)head * 65536 + (size_t)s * 64 + d;
                        Qhi[idx] = hb; Qlo[idx] = lb;
                    } else {
                        size_t idx = (size_t)head * 65536 + (size_t)(s >> 4) * 1024
                                   + (d >> 3) * 128 + (s & 15) * 8 + (d & 7);
                        Khi[idx] = hb; Klo[idx] = lb;
                    }
                }
            }
        }
    }
}

// ---------------------------------------------------------------------------
// Proj GEMM via MFMA — global_load_lds staging (kept).
// ---------------------------------------------------------------------------
__global__ __launch_bounds__(256) void proj_mfma_kernel(
    const unsigned short* __restrict__ Ag, const unsigned short* __restrict__ Bhg,
    const float* __restrict__ bias, float* __restrict__ OUT)
{
    __shared__ unsigned short Ah[128 * 32];
    __shared__ unsigned short Bh[128 * 32];
    const int tid = threadIdx.x;
    const int n0 = blockIdx.x * 128, m0 = blockIdx.y * 128;
    const int lane = tid & 63, l16 = lane & 15, quad = lane >> 4;
    const int w = tid >> 6, wm = w >> 1, wn = w & 1;

    f32x4 acc[4][4];
#pragma unroll
    for (int mi = 0; mi < 4; ++mi)
#pragma unroll
        for (int ni = 0; ni < 4; ++ni) acc[mi][ni] = (f32x4){0.f, 0.f, 0.f, 0.f};

    const int r0 = tid >> 2, kc = (tid & 3) * 8;
    const int r1 = r0 + 64;

    for (int k0 = 0; k0 < 768; k0 += 32) {
        __syncthreads();
        gl_lds16(&Ag[(size_t)(m0 + r0) * 768 + k0 + kc], &Ah[r0 * 32 + kc]);
        gl_lds16(&Ag[(size_t)(m0 + r1) * 768 + k0 + kc], &Ah[r1 * 32 + kc]);
        gl_lds16(&Bhg[(size_t)(n0 + r0) * 768 + k0 + kc], &Bh[r0 * 32 + kc]);
        gl_lds16(&Bhg[(size_t)(n0 + r1) * 768 + k0 + kc], &Bh[r1 * 32 + kc]);
        __syncthreads();

        bf16x8 fah[4];
#pragma unroll
        for (int mi = 0; mi < 4; ++mi)
            fah[mi] = *(const bf16x8*)&Ah[(wm * 64 + mi * 16 + l16) * 32 + quad * 8];
#pragma unroll
        for (int ni = 0; ni < 4; ++ni) {
            bf16x8 fbh = *(const bf16x8*)&Bh[(wn * 64 + ni * 16 + l16) * 32 + quad * 8];
#pragma unroll
            for (int mi = 0; mi < 4; ++mi)
                acc[mi][ni] = __builtin_amdgcn_mfma_f32_16x16x32_bf16(fah[mi], fbh, acc[mi][ni], 0, 0, 0);
        }
    }

#pragma unroll
    for (int mi = 0; mi < 4; ++mi)
#pragma unroll
        for (int ni = 0; ni < 4; ++ni) {
            int nb = n0 + wn * 64 + ni * 16 + l16;
            float bv = bias[nb];
#pragma unroll
            for (int r = 0; r < 4; ++r) {
                int m = m0 + wm * 64 + mi * 16 + quad * 4 + r;
                OUT[(size_t)m * 768 + nb] = acc[mi][ni][r] + bv;
            }
        }
}

// ---------------------------------------------------------------------------
// Attention, 1024 threads (16 waves), 64 KB LDS. R9 structure (213us) kept.
// This round, phase 2 only:
//  * count split SALU/VALU: 6 masks via s_bcnt (popcll), 10 masks via
//    v_bcnt_u32_b32 across FOUR parallel VGPR accumulators (chain depth ~5;
//    R1's failure was ONE 22-deep chain). Balances ~640 SALU vs ~620 VALU
//    cycles/CU/round instead of 1280 SALU-only.
//  * Illinois regula-falsi bracket update (counts at both ends known) with
//    t clamped to [0.10,0.90] and pure bisection after iter 24 -> typical
//    rounds ~6-9 vs ~15, worst case still collapses within the 64 cap.
//  Exactness unchanged: early-exit cnt==TOPK lands in the order-statistic
//  gap; collapse -> adjacent floats around v_k; same count predicate.
// ---------------------------------------------------------------------------
__global__ __launch_bounds__(1024, 8) void attn_kernel(
    const unsigned short* __restrict__ Qhi, const unsigned short* __restrict__ Qlo,
    const unsigned short* __restrict__ Khi, const unsigned short* __restrict__ Klo,
    const unsigned short* __restrict__ Vt, unsigned short* __restrict__ Aob)
{
    __shared__ float S[16 * 1024];   // 64 KB. Aliased: Pb bf16 (33 KB), partials
    unsigned short* Pb = (unsigned short*)S;   // [16][1032] shorts

    const int bid = blockIdx.x;
    const int wflat = (bid & 7) * 768 + (bid >> 3);
    const int head = wflat >> 6;     // 0..95
    const int qt = wflat & 63;       // 16-row q tile
    const int bb = head / 12, h = head - bb * 12;
    const int tid = threadIdx.x;
    const int w = tid >> 6, lane = tid & 63;
    const int l16 = lane & 15, quad = lane >> 4;

    const size_t hbase = (size_t)head * 65536;
    const unsigned short* Qhp = Qhi + hbase + (size_t)(qt * 16) * 64;
    const unsigned short* Qlp = Qlo + hbase + (size_t)(qt * 16) * 64;
    const unsigned short* Khp = Khi + hbase;
    const unsigned short* Klp = Klo + hbase;
    const unsigned short* Vp  = Vt + hbase;

    bf16x8 qh0, qh1, ql0, ql1;
    {
        int off = l16 * 64 + quad * 8;
        qh0 = *(const bf16x8*)(Qhp + off);
        qh1 = *(const bf16x8*)(Qhp + off + 32);
        ql0 = *(const bf16x8*)(Qlp + off);
        ql1 = *(const bf16x8*)(Qlp + off + 32);
    }

    // Per-lane fragment offset within a 1024-elem K tile (loop-invariant).
    const int kfo = quad * 128 + l16 * 8;

    // ---- Phase 1: scores for cols [w*64, w*64+64) ----
    for (int t = 0; t < 4; ++t) {
        int T = w * 4 + t;               // 16-col tile index
        int off = T * 1024 + kfo;
        bf16x8 kh0 = *(const bf16x8*)(Khp + off);
        bf16x8 kh1 = *(const bf16x8*)(Khp + off + 512);
        bf16x8 kl0 = *(const bf16x8*)(Klp + off);
        bf16x8 kl1 = *(const bf16x8*)(Klp + off + 512);
        f32x4 acc = {0.f, 0.f, 0.f, 0.f};
        acc = __builtin_amdgcn_mfma_f32_16x16x32_bf16(qh0, kh0, acc, 0, 0, 0);
        acc = __builtin_amdgcn_mfma_f32_16x16x32_bf16(qh1, kh1, acc, 0, 0, 0);
        acc = __builtin_amdgcn_mfma_f32_16x16x32_bf16(qh0, kl0, acc, 0, 0, 0);
        acc = __builtin_amdgcn_mfma_f32_16x16x32_bf16(qh1, kl1, acc, 0, 0, 0);
        acc = __builtin_amdgcn_mfma_f32_16x16x32_bf16(ql0, kh0, acc, 0, 0, 0);
        acc = __builtin_amdgcn_mfma_f32_16x16x32_bf16(ql1, kh1, acc, 0, 0, 0);
        int col0 = w * 64 + t * 16;
#pragma unroll
        for (int r = 0; r < 4; ++r)
            S[(quad * 4 + r) * 1024 + col0 + l16] = acc[r] * 0.125f;
    }
    __syncthreads();

    // ---- Phase 2: wave w owns row w; 16 values/lane ----
    float rs;
    {
        const float* Srow = &S[w << 10];
        float f[16];
        float m = -1e30f, mn = 1e30f;
#pragma unroll
        for (int i = 0; i < 4; ++i) {
            f32x4 v = *(const f32x4*)&Srow[(lane + (i << 6)) << 2];
#pragma unroll
            for (int k = 0; k < 4; ++k) {
                float x = v[k];
                f[i * 4 + k] = x;
                m = fmaxf(m, x);
                mn = fminf(mn, x);
            }
        }
        __syncthreads();   // all S fp32 reads done; Pb writes become safe

#pragma unroll
        for (int off = 32; off; off >>= 1) {
            m = fmaxf(m, __shfl_xor(m, off));
            mn = fminf(mn, __shfl_xor(mn, off));
        }

        // Threshold search: Illinois regula-falsi + SALU/VALU-split count.
        float lo = mn, hi = m;
        float clo = 1024.f, chi = 0.f;
        int side = 0;
#pragma unroll 1
        for (int it = 0; it < 64; ++it) {
            float t = 0.5f;
            float denom = clo - chi;
            if (it < 24 && denom > 0.f) {
                t = (clo - (float)TOPK) / denom;
                t = fminf(fmaxf(t, 0.10f), 0.90f);
            }
            float mid = lo + (hi - lo) * t;
            if (!(mid > lo && mid < hi)) break;   // bracket collapsed: exact

            // SALU path: 6 masks
            int cnts = 0;
#pragma unroll
            for (int i = 0; i < 6; ++i)
                cnts += (int)__popcll(__ballot(f[i] >= mid));
            // VALU path: 10 masks -> 20 v_bcnt over 4 parallel accumulators
            unsigned c0 = 0, c1 = 0, c2 = 0, c3 = 0;
#pragma unroll
            for (int i = 6; i < 16; i += 2) {
                unsigned long long mkA = __ballot(f[i] >= mid);
                unsigned long long mkB = __ballot(f[i + 1] >= mid);
                unsigned a0 = (unsigned)mkA, a1 = (unsigned)(mkA >> 32);
                unsigned b0 = (unsigned)mkB, b1 = (unsigned)(mkB >> 32);
                asm("v_bcnt_u32_b32 %0, %1, %0" : "+v"(c0) : "s"(a0));
                asm("v_bcnt_u32_b32 %0, %1, %0" : "+v"(c1) : "s"(a1));
                asm("v_bcnt_u32_b32 %0, %1, %0" : "+v"(c2) : "s"(b0));
                asm("v_bcnt_u32_b32 %0, %1, %0" : "+v"(c3) : "s"(b1));
            }
            unsigned cv = (c0 + c1) + (c2 + c3);
            int cnt = cnts + __builtin_amdgcn_readfirstlane((int)cv);

            if (cnt >= TOPK) {
                lo = mid; clo = (float)cnt;
                if (cnt == TOPK) break;           // mid in the gap: exact
                if (side == 1) chi = 0.5f * (chi + (float)TOPK);   // Illinois
                side = 1;
            } else {
                hi = mid; chi = (float)cnt;
                if (side == -1) clo = 0.5f * (clo + (float)TOPK);
                side = -1;
            }
        }
        const float thr = lo;

        // masked exp (base = row max), write P as bf16 into Pb
        float ssum = 0.f;
#pragma unroll
        for (int i = 0; i < 4; ++i) {
            us4 eh;
#pragma unroll
            for (int k = 0; k < 4; ++k) {
                float x = f[i * 4 + k];
                float ev = (x >= thr) ? exp2f((x - m) * LOG2E) : 0.f;
                ssum += ev;
                eh[k] = f2bf(ev);
            }
            *(us4*)&Pb[w * 1032 + 4 * lane + 256 * i] = eh;
        }
#pragma unroll
        for (int off = 32; off; off >>= 1) ssum += __shfl_xor(ssum, off);
        rs = ssum;
    }
    __syncthreads();

    // ---- Phase 3: partial O over k in [w*64, w*64+64) ----
    f32x4 oacc[4];
#pragma unroll
    for (int nt = 0; nt < 4; ++nt) oacc[nt] = (f32x4){0.f, 0.f, 0.f, 0.f};

    for (int step = 0; step < 2; ++step) {
        int k0 = w * 64 + step * 32;
        int K32 = w * 2 + step;          // 32-elem s-tile index
        bf16x8 a = *(const bf16x8*)&Pb[l16 * 1032 + k0 + quad * 8];
#pragma unroll
        for (int nt = 0; nt < 4; ++nt) {
            bf16x8 bfrag = *(const bf16x8*)(Vp + K32 * 2048 + nt * 512 + kfo);
            oacc[nt] = __builtin_amdgcn_mfma_f32_16x16x32_bf16(a, bfrag, oacc[nt], 0, 0, 0);
        }
    }
    __syncthreads();   // all Pb reads done; S region reusable

    // Stage A: waves 8..15 spill partials (rows 0..127, stride 68); rsum
    if (w >= 8) {
#pragma unroll
        for (int nt = 0; nt < 4; ++nt)
#pragma unroll
            for (int r = 0; r < 4; ++r)
                S[((w - 8) * 16 + quad * 4 + r) * 68 + nt * 16 + l16] = oacc[nt][r];
    }
    if (lane == 0) S[8704 + w] = rs;
    __syncthreads();

    // Stage B: waves 0..7 add the matching partial and write combined back
    if (w < 8) {
#pragma unroll
        for (int nt = 0; nt < 4; ++nt)
#pragma unroll
            for (int r = 0; r < 4; ++r) {
                int idx = (w * 16 + quad * 4 + r) * 68 + nt * 16 + l16;
                S[idx] = oacc[nt][r] + S[idx];
            }
    }
    __syncthreads();

    if (tid < 256) {
        int row = tid >> 4, ds = (tid & 15) * 4;
        f32x4 o = {0.f, 0.f, 0.f, 0.f};
#pragma unroll
        for (int ww = 0; ww < 8; ++ww)
            o += *(const f32x4*)&S[(ww * 16 + row) * 68 + ds];
        float inv = 1.f / S[8704 + row];
        int srow = qt * 16 + row;
        us4 res;
#pragma unroll
        for (int k = 0; k < 4; ++k) res[k] = f2bf(o[k] * inv);
        *(us4*)&Aob[((size_t)(bb * 1024 + srow)) * 768 + h * 64 + ds] = res;
    }
}

extern "C" void kernel_launch(void* const* d_in, const int* in_sizes, int n_in,
                              void* d_out, int out_size, void* d_ws, size_t ws_size,
                              hipStream_t stream)
{
    const float* X     = (const float*)d_in[0];
    const float* Wqkv  = (const float*)d_in[1];
    const float* bqkv  = (const float*)d_in[2];
    const float* Wproj = (const float*)d_in[3];
    const float* bproj = (const float*)d_in[4];
    float* out = (float*)d_out;

    unsigned short* us = (unsigned short*)d_ws;
    const size_t P = (size_t)8192 * 768;          // 6291456
    unsigned short* Xhi = us;
    unsigned short* Xlo = Xhi + P;
    unsigned short* Wqh = Xlo + P;                // [2304][768]
    unsigned short* Wql = Wqh + (size_t)2304 * 768;
    unsigned short* Wph = Wql + (size_t)2304 * 768;  // [768][768]
    unsigned short* Wpl = Wph + (size_t)768 * 768;
    unsigned short* Qhi = Wpl + (size_t)768 * 768;
    unsigned short* Qlo = Qhi + P;
    unsigned short* Khi = Qlo + P;
    unsigned short* Klo = Khi + P;
    unsigned short* Vt  = Klo + P;
    unsigned short* Aob = Xhi;   // reuse: X consumed by qkv before attn writes Aob

    cast_x_kernel<<<3072, 256, 0, stream>>>(X, Xhi, Xlo);
    transpose_split_kernel<<<dim3(72, 24), 256, 0, stream>>>(Wqkv, Wqh, Wql, 768, 2304);
    transpose_split_kernel<<<dim3(24, 24), 256, 0, stream>>>(Wproj, Wph, Wpl, 768, 768);
    qkv_mfma_kernel<<<dim3(18, 64), 256, 0, stream>>>(Xhi, Xlo, Wqh, Wql, bqkv,
                                                      Qhi, Qlo, Khi, Klo, Vt);
    attn_kernel<<<6144, 1024, 0, stream>>>(Qhi, Qlo, Khi, Klo, Vt, Aob);
    proj_mfma_kernel<<<dim3(6, 64), 256, 0, stream>>>(Aob, Wph, bproj, out);
}